// Round 5
// baseline (263.243 us; speedup 1.0000x reference)
//
#include <hip/hip_runtime.h>

typedef _Float16 half8    __attribute__((ext_vector_type(8)));
typedef float    floatx16 __attribute__((ext_vector_type(16)));
typedef float    float4v  __attribute__((ext_vector_type(4)));

#define K_DIM  256
#define N_DIM  256
#define NBLK   256
#define STRIPS 8      // 256 blocks * 8 waves * 8 strips * 32 rows = 524288

typedef const __attribute__((address_space(1))) void global_cv_t;
typedef __attribute__((address_space(3))) void lds_v_t;

// Build W^T in f16 bit patterns: W[k][n] = 2^shift[k][n] * (-1)^sign[k][n].
// shift is an exact integer in [-10,-1]; 2^shift is exact in f16.
__global__ __launch_bounds__(256) void build_wT(const float* __restrict__ shift,
                                                const float* __restrict__ sgn,
                                                unsigned short* __restrict__ wT) {
    int idx = blockIdx.x * 256 + threadIdx.x;   // idx = k*256 + n
    int k = idx >> 8, n = idx & 255;
    float sh = shift[idx];
    float sg = sgn[idx];
    int e = 15 + (int)sh;                       // f16 exponent field, 5..14
    unsigned short wv = (unsigned short)(((sg != 0.0f) ? 0x8000 : 0) | (e << 10));
    wT[n * 256 + k] = wv;                       // W^T[n][k], contiguous K
}

// Persistent streaming GEMM: one block per CU, one barrier ever, A streamed
// through 4 rotating register buffers (3 K=32 chunks always in flight).
__global__ __launch_bounds__(512, 2) void dense_shift_gemm(
        const float* __restrict__ x,
        const unsigned short* __restrict__ wT,
        const float* __restrict__ bias,
        float* __restrict__ out) {

    // Full W^T in LDS, f16, XOR-swizzled (slot s of row n holds slot s^(n&31)):
    // read side XORs the same -> lanes 0..31 hit 32 distinct slots, conflict-free.
    __shared__ __align__(16) unsigned short bLds[256 * 256];   // 128 KB

    const int t  = threadIdx.x;
    const int w  = t >> 6;            // wave 0..7
    const int l  = t & 63;
    const int ln = l & 31;
    const int hi = l >> 5;

    const long wrow = (long)blockIdx.x * (8 * STRIPS * 32) + (long)w * (STRIPS * 32);

    // ---- B init: per-wave DMA, 32 W^T rows per wave, source-swizzled ----
    {
        const int rr = l >> 5;
#pragma unroll
        for (int i = 0; i < 16; ++i) {
            const int n  = w * 32 + i * 2 + rr;
            const int sw = ln ^ (n & 31);                       // involution
            const unsigned short* g = wT + n * 256 + sw * 8;
            __builtin_amdgcn_global_load_lds(
                (global_cv_t*)g,
                (lds_v_t*)((char*)bLds + (w * 32 + i * 2) * 512),
                16, 0, 0);
        }
    }

    // A-fragment base: lane covers row (wrow + ln), k-offset hi*8.
    const float* ax = x + (wrow + ln) * (long)K_DIM + hi * 8;

    float4v B0[4], B1[4], B2[4], B3[4];

    // Load one K=32 chunk (4 x dwordx4 = 64 B/lane-row-half) of strip base b_.
#define LOADR(R_, b_, kc_) do {                                \
        R_[0] = *(const float4v*)((b_) + (kc_) * 32);          \
        R_[1] = *(const float4v*)((b_) + (kc_) * 32 + 4);      \
        R_[2] = *(const float4v*)((b_) + (kc_) * 32 + 16);     \
        R_[3] = *(const float4v*)((b_) + (kc_) * 32 + 20);     \
        __builtin_amdgcn_sched_barrier(0);                     \
    } while (0)

    // ---- prologue: strip 0 chunks 0..2 in flight before the barrier ----
    LOADR(B0, ax, 0);
    LOADR(B1, ax, 1);
    LOADR(B2, ax, 2);

    float bv[8];
#pragma unroll
    for (int nb = 0; nb < 8; ++nb) bv[nb] = bias[nb * 32 + ln];

    __syncthreads();   // the ONLY barrier: B-LDS ready

    const char* bl = (const char*)bLds;

    // One K=32 chunk: 2 k-slices, 8 n-blocks. B from conflict-free LDS.
#define COMPUTE(R_, kc_) do {                                                 \
        _Pragma("unroll")                                                     \
        for (int ks = 0; ks < 2; ++ks) {                                      \
            float4v f0 = R_[2 * ks], f1 = R_[2 * ks + 1];                     \
            half8 a;                                                          \
            a[0] = (_Float16)f0[0]; a[1] = (_Float16)f0[1];                   \
            a[2] = (_Float16)f0[2]; a[3] = (_Float16)f0[3];                   \
            a[4] = (_Float16)f1[0]; a[5] = (_Float16)f1[1];                   \
            a[6] = (_Float16)f1[2]; a[7] = (_Float16)f1[3];                   \
            _Pragma("unroll")                                                 \
            for (int nb = 0; nb < 8; ++nb) {                                  \
                const int g_ = (kc_) * 4 + ks * 2 + hi;                       \
                half8 b = *(const half8*)(bl + (size_t)nb * 16384             \
                              + (size_t)ln * 512 + ((size_t)(g_ ^ ln) << 4)); \
                acc[nb] = __builtin_amdgcn_mfma_f32_32x32x16_f16(a, b, acc[nb], 0, 0, 0); \
            }                                                                 \
        }                                                                     \
    } while (0)

    float* op = out + (wrow + 4 * hi) * (long)N_DIM + ln;

#pragma unroll 1
    for (int s = 0; s < STRIPS; ++s) {
        // next strip's base; last strip re-reads own rows (in-bounds, unused)
        const float* axn = (s == STRIPS - 1) ? ax : (ax + 32 * K_DIM);

        floatx16 acc[8];
#pragma unroll
        for (int nb = 0; nb < 8; ++nb)
#pragma unroll
            for (int r = 0; r < 16; ++r) acc[nb][r] = bv[nb];   // bias pre-folded

        // 8 chunks; rotation period 4 == static register names in a real loop.
        LOADR(B3, ax,  3);  COMPUTE(B0, 0);
        LOADR(B0, ax,  4);  COMPUTE(B1, 1);
        LOADR(B1, ax,  5);  COMPUTE(B2, 2);
        LOADR(B2, ax,  6);  COMPUTE(B3, 3);
        LOADR(B3, ax,  7);  COMPUTE(B0, 4);
        LOADR(B0, axn, 0);  COMPUTE(B1, 5);
        LOADR(B1, axn, 1);  COMPUTE(B2, 6);
        LOADR(B2, axn, 2);  COMPUTE(B3, 7);

        // store strip (fire-and-forget). C: col=l&31, row=(r&3)+8*(r>>2)+4*(l>>5).
#pragma unroll
        for (int nb = 0; nb < 8; ++nb) {
#pragma unroll
            for (int r = 0; r < 16; ++r) {
                const int row = (r & 3) + 8 * (r >> 2);
                op[(long)row * N_DIM + nb * 32] = acc[nb][r];
            }
        }

        ax += 32 * K_DIM;
        op += 32 * (long)N_DIM;
    }

#undef LOADR
#undef COMPUTE
}

extern "C" void kernel_launch(void* const* d_in, const int* in_sizes, int n_in,
                              void* d_out, int out_size, void* d_ws, size_t ws_size,
                              hipStream_t stream) {
    const float* x     = (const float*)d_in[0];
    const float* shift = (const float*)d_in[1];
    const float* sgn   = (const float*)d_in[2];
    const float* bias  = (const float*)d_in[3];
    float* out = (float*)d_out;
    unsigned short* wT = (unsigned short*)d_ws;   // 256*256*2 = 128 KB scratch

    build_wT<<<256, 256, 0, stream>>>(shift, sgn, wT);

    // 256 blocks (1 per CU) x 8 waves x 8 strips x 32 rows = 524288 rows.
    dense_shift_gemm<<<NBLK, 512, 0, stream>>>(x, wT, bias, out);
}

// Round 6
// 222.701 us; speedup vs baseline: 1.1820x; 1.1820x over previous
//
#include <hip/hip_runtime.h>

typedef _Float16 half8    __attribute__((ext_vector_type(8)));
typedef float    floatx16 __attribute__((ext_vector_type(16)));
typedef float    float4v  __attribute__((ext_vector_type(4)));

#define K_DIM 256
#define N_DIM 256
#define NBLK  2048    // 2048 blocks * 8 waves * 32 rows = 524288 rows

typedef const __attribute__((address_space(1))) void global_cv_t;
typedef __attribute__((address_space(3))) void lds_v_t;

// Build W^T in f16 bit patterns: W[k][n] = 2^shift[k][n] * (-1)^sign[k][n].
// shift is an exact integer in [-10,-1]; 2^shift is exact in f16.
__global__ __launch_bounds__(256) void build_wT(const float* __restrict__ shift,
                                                const float* __restrict__ sgn,
                                                unsigned short* __restrict__ wT) {
    int idx = blockIdx.x * 256 + threadIdx.x;   // idx = k*256 + n
    int k = idx >> 8, n = idx & 255;
    float sh = shift[idx];
    float sg = sgn[idx];
    int e = 15 + (int)sh;                       // f16 exponent field, 5..14
    unsigned short wv = (unsigned short)(((sg != 0.0f) ? 0x8000 : 0) | (e << 10));
    wT[n * 256 + k] = wv;                       // W^T[n][k], contiguous K
}

// Bulk-load generation GEMM: ALL of a wave's strip A (32 dwordx4) + the B-DMA
// are in flight before the single barrier; HBM latency paid once per block.
// After the barrier: pure compute with stores spread across it.
__global__ __launch_bounds__(512, 2) void dense_shift_gemm(
        const float* __restrict__ x,
        const unsigned short* __restrict__ wT,
        const float* __restrict__ bias,
        float* __restrict__ out) {

    // Full W^T in LDS, f16, XOR-swizzled (slot s of row n holds slot s^(n&31)):
    // read side XORs the same -> lanes 0..31 hit distinct slots; within any
    // 8-lane phase of ds_read_b128 the 32 dwords cover all 32 banks once.
    __shared__ __align__(16) unsigned short bLds[256 * 256];   // 128 KB

    const int t  = threadIdx.x;
    const int w  = t >> 6;            // wave 0..7
    const int l  = t & 63;
    const int ln = l & 31;
    const int hi = l >> 5;

    const long row0 = ((long)blockIdx.x * 8 + w) * 32;   // this wave's 32 rows

    // ---- B init: per-wave DMA, 32 W^T rows per wave, source-swizzled.
    // global_load_lds dest = uniform base + lane*16: lanes 0..31 -> row n0
    // slots 0..31, lanes 32..63 -> row n0+1. Source pre-swizzled to match. ----
    {
        const int rr = l >> 5;
#pragma unroll
        for (int i = 0; i < 16; ++i) {
            const int n  = w * 32 + i * 2 + rr;
            const int sw = ln ^ (n & 31);                       // involution
            const unsigned short* g = wT + n * 256 + sw * 8;
            __builtin_amdgcn_global_load_lds(
                (global_cv_t*)g,
                (lds_v_t*)((char*)bLds + (w * 32 + i * 2) * 512),
                16, 0, 0);
        }
    }

    // ---- A: issue the ENTIRE strip (32 x dwordx4 = 512 B/lane) up front.
    // 32 A-loads + 16 B-DMA = 48 outstanding vmem ops (< vmcnt cap 63). ----
    const float* ax = x + (row0 + ln) * (long)K_DIM + hi * 8;
    float4v F[32];
#pragma unroll
    for (int ks = 0; ks < 16; ++ks) {
        F[2 * ks]     = *(const float4v*)(ax + ks * 16);
        F[2 * ks + 1] = *(const float4v*)(ax + ks * 16 + 4);
    }
    __builtin_amdgcn_sched_barrier(0);

    float bv[8];
#pragma unroll
    for (int nb = 0; nb < 8; ++nb) bv[nb] = bias[nb * 32 + ln];

    __syncthreads();   // the ONLY barrier: drains B-DMA and all A-loads at once

    // ---- cvt f32 -> f16 fragments (F dies as a16 is born: peak ~160 VGPR) ----
    half8 a16[16];
#pragma unroll
    for (int ks = 0; ks < 16; ++ks) {
        float4v f0 = F[2 * ks], f1 = F[2 * ks + 1];
        half8 a;
        a[0] = (_Float16)f0[0]; a[1] = (_Float16)f0[1];
        a[2] = (_Float16)f0[2]; a[3] = (_Float16)f0[3];
        a[4] = (_Float16)f1[0]; a[5] = (_Float16)f1[1];
        a[6] = (_Float16)f1[2]; a[7] = (_Float16)f1[3];
        a16[ks] = a;
    }

    const char* bl = (const char*)bLds;
    float* op = out + (row0 + 4 * hi) * (long)N_DIM + ln;

    // ---- compute: nb-pairs for MFMA ILP; stores fire after each pair and
    // overlap the next pair's ds_read+MFMA (never waited on in this block) ----
#pragma unroll
    for (int p = 0; p < 4; ++p) {
        const int nb0 = 2 * p, nb1 = 2 * p + 1;

        floatx16 acc0, acc1;
#pragma unroll
        for (int r = 0; r < 16; ++r) { acc0[r] = bv[nb0]; acc1[r] = bv[nb1]; }

#pragma unroll
        for (int ks = 0; ks < 16; ++ks) {
            const size_t so = (size_t)ln * 512 + ((size_t)((2 * ks + hi) ^ ln) << 4);
            half8 b0 = *(const half8*)(bl + (size_t)nb0 * 16384 + so);
            half8 b1 = *(const half8*)(bl + (size_t)nb1 * 16384 + so);
            acc0 = __builtin_amdgcn_mfma_f32_32x32x16_f16(a16[ks], b0, acc0, 0, 0, 0);
            acc1 = __builtin_amdgcn_mfma_f32_32x32x16_f16(a16[ks], b1, acc1, 0, 0, 0);
        }

        // C layout: col = l&31, row = (r&3) + 8*(r>>2) + 4*(l>>5).
#pragma unroll
        for (int r = 0; r < 16; ++r) {
            const int row = (r & 3) + 8 * (r >> 2);
            op[(long)row * N_DIM + nb0 * 32] = acc0[r];
            op[(long)row * N_DIM + nb1 * 32] = acc1[r];
        }
    }
}

extern "C" void kernel_launch(void* const* d_in, const int* in_sizes, int n_in,
                              void* d_out, int out_size, void* d_ws, size_t ws_size,
                              hipStream_t stream) {
    const float* x     = (const float*)d_in[0];
    const float* shift = (const float*)d_in[1];
    const float* sgn   = (const float*)d_in[2];
    const float* bias  = (const float*)d_in[3];
    float* out = (float*)d_out;
    unsigned short* wT = (unsigned short*)d_ws;   // 256*256*2 = 128 KB scratch

    build_wT<<<256, 256, 0, stream>>>(shift, sgn, wT);

    dense_shift_gemm<<<NBLK, 512, 0, stream>>>(x, wT, bias, out);
}